// Round 9
// baseline (434687.305 us; speedup 1.0000x reference)
//
#include <hip/hip_runtime.h>
#include <hip/hip_bf16.h>
#include <cstdint>
#include <cstddef>

#define VOCAB 32000
#define HIDDEN 1024
#define BATCH 32
#define SEQ 128

typedef __attribute__((ext_vector_type(8))) short short8v;
typedef __attribute__((ext_vector_type(4))) float float4v;
typedef __attribute__((ext_vector_type(2))) unsigned int uint2v;

__device__ __forceinline__ unsigned short f2bf(float f) {
    unsigned int x = __float_as_uint(f);
    unsigned int r = x + 0x7fffu + ((x >> 16) & 1u);  // RNE
    return (unsigned short)(r >> 16);
}

// ---------------- pre-conversion: transpose fp32 [rows][cols] -> bf16 [cols][rows] ----------------
__global__ __launch_bounds__(256) void k_transpose_bf(const float* __restrict__ in,
                                                      unsigned short* __restrict__ out,
                                                      int cols, int rows) {
    __shared__ float tile[64][65];
    const int jb = blockIdx.x;
    const int kb = blockIdx.y;
    const int t  = threadIdx.x;
    const int c  = t & 63;
    const int r0 = (t >> 6) * 16;
#pragma unroll
    for (int i = 0; i < 16; i++) {
        int r = r0 + i;
        tile[r][c] = in[(size_t)(kb * 64 + r) * cols + jb * 64 + c];
    }
    __syncthreads();
#pragma unroll
    for (int i = 0; i < 16; i++) {
        int r = r0 + i;
        out[(size_t)(jb * 64 + r) * rows + kb * 64 + c] = f2bf(tile[c][r]);
    }
}

// ---------------- persistent recurrence kernel (XCD-local, producer-push notify) ----------------
// Launch 1024 blocks x 64 threads. A block reads HW_REG_XCC_ID and claims a slot
// on its XCD; XCD g<2 hosts group g (batches [g*16,+16)); slots 0..63 = j-slices
// (16 cols each); everyone else exits. 72.5 KB LDS -> 2 blocks/CU -> the first 64
// blocks STARTED on an XCD are the claimers -> co-resident by construction.
// All exchange stays in that XCD's L2:
//  - data: plain stores (write-through L1 -> local L2), drained by vmcnt(0)
//  - notify: each of 64 lanes stores the tag into one consumer's PRIVATE mailbox
//    slot (producer-push, no aggregator, 64 distinct lines)
//  - poll: atomic fetch_add(p,0) — atomics execute at the TCC/L2, so they can
//    NEVER read a stale L1 line (the r7 failure mechanism). Workgroup scope =
//    no sc1 = stays at the local L2 where producers' stores land.
// Consumers read tile data with plain cached loads: every line is write-once per
// call (rotating buffers) and first touched after its poll; cross-call values are
// identical (deterministic) and dispatch boundaries invalidate caches.
// ALL spins are watchdog-capped: a protocol failure ends as wrong absmax, not a hang.

#define WAIT_VM0 asm volatile("s_waitcnt vmcnt(0)" ::: "memory")
#define LGKM0    asm volatile("s_waitcnt lgkmcnt(0)" ::: "memory")

__device__ __forceinline__ void mbox_poll(unsigned int* row, unsigned int tag) {
    unsigned int* p = row + (threadIdx.x & 63) * 2;  // 8B-stride entries
    int guard = 0;
    while (true) {
        unsigned int v = __hip_atomic_fetch_add(p, 0u, __ATOMIC_RELAXED,
                                                __HIP_MEMORY_SCOPE_WORKGROUP);
        if (__all((int)(v >= tag))) break;
        if (++guard > 16384) break;  // watchdog: ~400x above healthy wait
        __builtin_amdgcn_s_sleep(1);
    }
}

__global__ __launch_bounds__(64, 1) void k_rnn(const int* __restrict__ x,
                                               const float* __restrict__ state,
                                               const unsigned short* __restrict__ wrt,
                                               const unsigned short* __restrict__ wzt,
                                               const unsigned short* __restrict__ wht,
                                               const float* __restrict__ W_xr, const float* __restrict__ b_r,
                                               const float* __restrict__ W_xz, const float* __restrict__ b_z,
                                               const float* __restrict__ W_xh, const float* __restrict__ b_h,
                                               unsigned short* __restrict__ hall,   // [128][32][1024]
                                               unsigned short* __restrict__ rhall,  // [128][32][1024]
                                               float* __restrict__ hstate_out,      // [32][1024]
                                               unsigned int* __restrict__ mbox,     // [2][64][64] stride-8B
                                               unsigned int* __restrict__ claim) {  // [8]
    // ---- XCD-local role claiming ----
    unsigned int xcc;
    asm volatile("s_getreg_b32 %0, hwreg(HW_REG_XCC_ID)" : "=s"(xcc));
    xcc &= 7u;
    unsigned int slot = 0;
    if (threadIdx.x == 0) slot = atomicAdd(&claim[xcc], 1u);
    slot = (unsigned int)__shfl((int)slot, 0);
    if (xcc >= 2u || slot >= 64u) return;

    const int g   = (int)xcc;
    const int jsl = (int)slot;
    const int j0  = jsl * 16;
    const int b0  = g * 16;
    const int l   = threadIdx.x;  // 0..63
    const int llo = l & 15;
    const int lhi = l >> 4;
    const int jg  = j0 + llo;

    unsigned int* gm    = mbox + g * 64 * 64 * 2;           // this group's mailboxes
    unsigned int* myrow = gm + jsl * 64 * 2;                // my private row (poll target)

    __shared__ short8v wlds[2][32][64];      // 64 KB: W_hr, W_hz B-fragments
    __shared__ int xs[16 * SEQ];             // 8 KB: own group's tokens
    __shared__ unsigned short pack[16 * 16]; // 512 B exchange tile

    // ---- one-time: wr/wz -> LDS, tokens -> LDS ----
#pragma unroll
    for (int i = 0; i < 32; i++) {
        const size_t off = (size_t)jg * HIDDEN + i * 32 + lhi * 8;
        wlds[0][i][l] = *(const short8v*)&wrt[off];
        wlds[1][i][l] = *(const short8v*)&wzt[off];
    }
    for (int i = l; i < 16 * SEQ; i += 64)
        xs[i] = x[(size_t)(b0 + (i >> 7)) * SEQ + (i & 127)];

    const float brv = b_r[jg], bzv = b_z[jg], bhv = b_h[jg];
    float4v hO;
#pragma unroll
    for (int q = 0; q < 4; q++) hO[q] = state[(b0 + 4 * lhi + q) * HIDDEN + jg];
    LGKM0;  // LDS preload visible to own wave's reads

    for (int t = 0; t < SEQ; t++) {
        unsigned short* rhp = rhall + (size_t)t * BATCH * HIDDEN;
        unsigned short* hp  = hall + (size_t)t * BATCH * HIDDEN;

        // embedding gathers issued BEFORE the wait (latency hides under it)
        int tok[4];
#pragma unroll
        for (int q = 0; q < 4; q++) tok[q] = xs[(4 * lhi + q) * SEQ + t];
        float xr[4], xz[4], xh[4];
#pragma unroll
        for (int q = 0; q < 4; q++) {
            xr[q] = W_xr[(size_t)tok[q] * HIDDEN + jg];
            xz[q] = W_xz[(size_t)tok[q] * HIDDEN + jg];
            xh[q] = W_xh[(size_t)tok[q] * HIDDEN + jg];
        }

        // ---- Phase A: wait h(t-1), compute r,z ----
        short8v af[32];
        if (t == 0) {
            // build h(-1) fragments from fp32 state directly (one-time)
#pragma unroll
            for (int i = 0; i < 32; i++) {
                const float* sp = &state[(size_t)(b0 + llo) * HIDDEN + i * 32 + lhi * 8];
                short8v v;
#pragma unroll
                for (int e = 0; e < 8; e++) v[e] = (short)f2bf(sp[e]);
                af[i] = v;
            }
        } else {
            mbox_poll(myrow, 2u * (unsigned)t);
            const unsigned short* hprev = hall + (size_t)(t - 1) * BATCH * HIDDEN;
#pragma unroll
            for (int i = 0; i < 32; i++)
                af[i] = *(const short8v*)&hprev[(b0 + llo) * HIDDEN + i * 32 + lhi * 8];
        }

        float4v aR0 = {0.f, 0.f, 0.f, 0.f}, aR1 = {0.f, 0.f, 0.f, 0.f};
        float4v aZ0 = {0.f, 0.f, 0.f, 0.f}, aZ1 = {0.f, 0.f, 0.f, 0.f};
#pragma unroll
        for (int i = 0; i < 32; i += 2) {
            aR0 = __builtin_amdgcn_mfma_f32_16x16x32_bf16(af[i],     wlds[0][i][l],     aR0, 0, 0, 0);
            aZ0 = __builtin_amdgcn_mfma_f32_16x16x32_bf16(af[i],     wlds[1][i][l],     aZ0, 0, 0, 0);
            aR1 = __builtin_amdgcn_mfma_f32_16x16x32_bf16(af[i + 1], wlds[0][i + 1][l], aR1, 0, 0, 0);
            aZ1 = __builtin_amdgcn_mfma_f32_16x16x32_bf16(af[i + 1], wlds[1][i + 1][l], aZ1, 0, 0, 0);
        }

        float4v zv;
#pragma unroll
        for (int q = 0; q < 4; q++) {
            float sr = aR0[q] + aR1[q] + xr[q] + brv;
            float sz = aZ0[q] + aZ1[q] + xz[q] + bzv;
            float rv = 1.f / (1.f + __expf(-sr));
            zv[q]    = 1.f / (1.f + __expf(-sz));
            pack[(4 * lhi + q) * 16 + llo] = f2bf(rv * hO[q]);
        }
        LGKM0;
        __builtin_amdgcn_wave_barrier();
        {   // publish rh tile: plain 8B stores -> local L2, drain, push-notify
            uint2v v = *(const uint2v*)&pack[(l >> 2) * 16 + (l & 3) * 4];
            *(uint2v*)&rhp[(b0 + (l >> 2)) * HIDDEN + j0 + (l & 3) * 4] = v;
            WAIT_VM0;
            __hip_atomic_store(&gm[(l * 64 + jsl) * 2], 2u * (unsigned)t + 1u,
                               __ATOMIC_RELAXED, __HIP_MEMORY_SCOPE_WORKGROUP);
        }

        // stream W_hh for this step (independent of rh) — hides under the wait
        short8v wh[32];
#pragma unroll
        for (int i = 0; i < 32; i++)
            wh[i] = *(const short8v*)&wht[(size_t)jg * HIDDEN + i * 32 + lhi * 8];

        // ---- Phase B: wait rh, compute candidate + update ----
        mbox_poll(myrow, 2u * (unsigned)t + 1u);

        short8v ar[32];
#pragma unroll
        for (int i = 0; i < 32; i++)
            ar[i] = *(const short8v*)&rhp[(b0 + llo) * HIDDEN + i * 32 + lhi * 8];

        float4v aC0 = {0.f, 0.f, 0.f, 0.f}, aC1 = {0.f, 0.f, 0.f, 0.f};
#pragma unroll
        for (int i = 0; i < 32; i += 2) {
            aC0 = __builtin_amdgcn_mfma_f32_16x16x32_bf16(ar[i],     wh[i],     aC0, 0, 0, 0);
            aC1 = __builtin_amdgcn_mfma_f32_16x16x32_bf16(ar[i + 1], wh[i + 1], aC1, 0, 0, 0);
        }
#pragma unroll
        for (int q = 0; q < 4; q++) {
            float a = aC0[q] + aC1[q] + xh[q] + bhv;
            a = fminf(15.f, fmaxf(-15.f, a));
            float e2   = __expf(2.f * a);
            float cand = (e2 - 1.f) / (e2 + 1.f);
            float hn   = zv[q] * hO[q] + (1.f - zv[q]) * cand;
            hO[q]      = hn;
            pack[(4 * lhi + q) * 16 + llo] = f2bf(hn);
        }
        LGKM0;
        __builtin_amdgcn_wave_barrier();
        {   // publish h tile into hall[t] (also the GEMM A matrix)
            uint2v v = *(const uint2v*)&pack[(l >> 2) * 16 + (l & 3) * 4];
            *(uint2v*)&hp[(b0 + (l >> 2)) * HIDDEN + j0 + (l & 3) * 4] = v;
            WAIT_VM0;
            __hip_atomic_store(&gm[(l * 64 + jsl) * 2], 2u * (unsigned)t + 2u,
                               __ATOMIC_RELAXED, __HIP_MEMORY_SCOPE_WORKGROUP);
        }
    }

#pragma unroll
    for (int q = 0; q < 4; q++)
        hstate_out[(b0 + 4 * lhi + q) * HIDDEN + jg] = hO[q];
}

// ---------------- output-projection GEMM ----------------
#define BM 128
#define BN 128
#define BK 64

__device__ __forceinline__ void gload_lds16(const void* g, void* l) {
    __builtin_amdgcn_global_load_lds((const __attribute__((address_space(1))) void*)g,
                                     (__attribute__((address_space(3))) void*)l, 16, 0, 0);
}

__global__ __launch_bounds__(256, 2) void k_gemm(const unsigned short* __restrict__ A,
                                                 const unsigned short* __restrict__ B,
                                                 const float* __restrict__ bo,
                                                 float* __restrict__ out) {
    __shared__ unsigned short As[BM * BK];
    __shared__ unsigned short Bs[BN * BK];
    const int wg   = blockIdx.y * 250 + blockIdx.x;
    const int swz  = (wg & 7) * 1000 + (wg >> 3);
    const int nb   = swz % 250;
    const int mb   = swz / 250;
    const int tid  = threadIdx.x;
    const int lane = tid & 63;
    const int w    = tid >> 6;
    const int wm   = w >> 1, wn = w & 1;
    const int row0 = mb * BM, col0 = nb * BN;

    float4v acc[4][4];
#pragma unroll
    for (int i = 0; i < 4; i++)
#pragma unroll
        for (int j = 0; j < 4; j++) acc[i][j] = float4v{0.f, 0.f, 0.f, 0.f};

    for (int kt = 0; kt < HIDDEN / BK; kt++) {
#pragma unroll
        for (int i = 0; i < 4; i++) {
            int s   = i * 256 + tid;
            int row = s >> 3;
            int off = (s & 7) * 8;
            gload_lds16(A + (size_t)(row0 + row) * HIDDEN + kt * BK + off, &As[s * 8]);
            gload_lds16(B + (size_t)(col0 + row) * HIDDEN + kt * BK + off, &Bs[s * 8]);
        }
        __syncthreads();
#pragma unroll
        for (int kk = 0; kk < 2; kk++) {
            short8v af[4], bf[4];
#pragma unroll
            for (int i = 0; i < 4; i++) {
                int ar = wm * 64 + i * 16 + (lane & 15);
                af[i] = *(short8v*)&As[ar * BK + kk * 32 + (lane >> 4) * 8];
                int br = wn * 64 + i * 16 + (lane & 15);
                bf[i] = *(short8v*)&Bs[br * BK + kk * 32 + (lane >> 4) * 8];
            }
#pragma unroll
            for (int i = 0; i < 4; i++)
#pragma unroll
                for (int j = 0; j < 4; j++)
                    acc[i][j] = __builtin_amdgcn_mfma_f32_16x16x32_bf16(af[i], bf[j], acc[i][j], 0, 0, 0);
        }
        __syncthreads();
    }
#pragma unroll
    for (int i = 0; i < 4; i++) {
        int grow = row0 + wm * 64 + i * 16 + (lane >> 4) * 4;
#pragma unroll
        for (int j = 0; j < 4; j++) {
            int gcol   = col0 + wn * 64 + j * 16 + (lane & 15);
            float bias = bo[gcol];
#pragma unroll
            for (int r = 0; r < 4; r++) {
                out[(size_t)(grow + r) * VOCAB + gcol] = acc[i][j][r] + bias;
            }
        }
    }
}

// ---------------- host ----------------

extern "C" void kernel_launch(void* const* d_in, const int* in_sizes, int n_in,
                              void* d_out, int out_size, void* d_ws, size_t ws_size,
                              hipStream_t stream) {
    const int*   x     = (const int*)d_in[0];
    const float* state = (const float*)d_in[1];
    const float* W_xr  = (const float*)d_in[2];
    const float* W_hr  = (const float*)d_in[3];
    const float* b_r   = (const float*)d_in[4];
    const float* W_xz  = (const float*)d_in[5];
    const float* W_hz  = (const float*)d_in[6];
    const float* b_z   = (const float*)d_in[7];
    const float* W_xh  = (const float*)d_in[8];
    const float* W_hh  = (const float*)d_in[9];
    const float* b_h   = (const float*)d_in[10];
    const float* W_ho  = (const float*)d_in[11];
    const float* b_o   = (const float*)d_in[12];

    float* out    = (float*)d_out;
    float* hstate = out + (size_t)SEQ * BATCH * VOCAB;

    // ws layout (bytes):
    //   0        : hall  bf16 [128][32][1024]   8,388,608  (= GEMM A matrix)
    //   8388608  : rhall bf16 [128][32][1024]   8,388,608
    //   16777216 : bt    bf16 [32000][1024]    65,536,000
    //   82313216 : wrt   bf16 [1024][1024]      2,097,152
    //   84410368 : wzt   bf16                   2,097,152
    //   86507520 : wht   bf16                   2,097,152
    //   88604672 : mbox  u32  [2][64][64] x8B      65,536
    //   88670208 : claim u32  [8]                      32    total 88,670,240
    char* ws = (char*)d_ws;
    unsigned short* hall  = (unsigned short*)ws;
    unsigned short* rhall = (unsigned short*)(ws + 8388608);
    unsigned short* bt    = (unsigned short*)(ws + 16777216);
    unsigned short* wrt   = (unsigned short*)(ws + 82313216);
    unsigned short* wzt   = (unsigned short*)(ws + 84410368);
    unsigned short* wht   = (unsigned short*)(ws + 86507520);
    unsigned int*   mbox  = (unsigned int*)(ws + 88604672);
    unsigned int*   claim = (unsigned int*)(ws + 88670208);

    hipMemsetAsync(mbox, 0, 65536 + 32, stream);
    k_transpose_bf<<<dim3(16, 16), 256, 0, stream>>>(W_hr, wrt, HIDDEN, HIDDEN);
    k_transpose_bf<<<dim3(16, 16), 256, 0, stream>>>(W_hz, wzt, HIDDEN, HIDDEN);
    k_transpose_bf<<<dim3(16, 16), 256, 0, stream>>>(W_hh, wht, HIDDEN, HIDDEN);
    k_transpose_bf<<<dim3(500, 16), 256, 0, stream>>>(W_ho, bt, VOCAB, HIDDEN);

    k_rnn<<<1024, 64, 0, stream>>>(x, state, wrt, wzt, wht, W_xr, b_r, W_xz, b_z, W_xh, b_h,
                                   hall, rhall, hstate, mbox, claim);

    k_gemm<<<dim3(250, 32), 256, 0, stream>>>(hall, bt, b_o, out);
}

// Round 10
// 1295.210 us; speedup vs baseline: 335.6115x; 335.6115x over previous
//
#include <hip/hip_runtime.h>
#include <hip/hip_bf16.h>
#include <cstdint>
#include <cstddef>

#define VOCAB 32000
#define HIDDEN 1024
#define BATCH 32
#define SEQ 128

typedef __attribute__((ext_vector_type(8))) short short8v;
typedef __attribute__((ext_vector_type(4))) float float4v;
typedef __attribute__((ext_vector_type(2))) unsigned int uint2v;

__device__ __forceinline__ unsigned short f2bf(float f) {
    unsigned int x = __float_as_uint(f);
    unsigned int r = x + 0x7fffu + ((x >> 16) & 1u);  // RNE
    return (unsigned short)(r >> 16);
}

// ---------------- pre-conversion: transpose fp32 [rows][cols] -> bf16 [cols][rows] ----------------
__global__ __launch_bounds__(256) void k_transpose_bf(const float* __restrict__ in,
                                                      unsigned short* __restrict__ out,
                                                      int cols, int rows) {
    __shared__ float tile[64][65];
    const int jb = blockIdx.x;
    const int kb = blockIdx.y;
    const int t  = threadIdx.x;
    const int c  = t & 63;
    const int r0 = (t >> 6) * 16;
#pragma unroll
    for (int i = 0; i < 16; i++) {
        int r = r0 + i;
        tile[r][c] = in[(size_t)(kb * 64 + r) * cols + jb * 64 + c];
    }
    __syncthreads();
#pragma unroll
    for (int i = 0; i < 16; i++) {
        int r = r0 + i;
        out[(size_t)(jb * 64 + r) * rows + kb * 64 + c] = f2bf(tile[c][r]);
    }
}

__global__ __launch_bounds__(256) void k_init_hbf(const float* __restrict__ state,
                                                  unsigned short* __restrict__ hinit) {
    int i = blockIdx.x * 256 + threadIdx.x;
    if (i < BATCH * HIDDEN) hinit[i] = f2bf(state[i]);
}

// ---------------- persistent recurrence kernel (direct producer-push notify) ----------------
// 128 blocks x 64 threads (1 wave each). group g = bid>>6 owns batches [g*16,+16);
// block owns j-cols [jsl*16,+16). Weights in LDS (96 KB of MFMA B-fragments).
// Exchange buffers ROTATE per step (write-once): rh -> rhall[t], h -> hall[t]
// (hall doubles as the GEMM A matrix); consumers use plain cached loads (first
// touch of any line is after its poll; cross-replay residue holds identical
// values since the computation is deterministic).
// Producers write data through (sc0 sc1), drain vmcnt(0) (data at MALL), then
// ALL 64 lanes push the tag directly into the 64 consumers' PRIVATE mailbox
// slots (agent-scope relaxed atomic stores -- the r5/r6-proven primitive).
// mbox[g][cons][prod] u32: each consumer polls only its own 256B row -> 4 cache
// lines with exactly ONE poller each (no same-line poll contention), written by
// 64 distinct producers at distinct addresses. No aggregator hop.
// All spins watchdog-capped: protocol failure = wrong absmax, never a hang.

#define WAIT_VM0 asm volatile("s_waitcnt vmcnt(0)" ::: "memory")
#define LGKM0    asm volatile("s_waitcnt lgkmcnt(0)" ::: "memory")

#define ST8_WT(P, V) \
    asm volatile("global_store_dwordx2 %0, %1, off sc0 sc1" ::"v"(P), "v"(V) : "memory")

__device__ __forceinline__ void row_poll(const unsigned int* row, unsigned int tag) {
    const unsigned int* p = row + (threadIdx.x & 63);
    int guard = 0;
    while (true) {
        unsigned int v = __hip_atomic_load(p, __ATOMIC_RELAXED, __HIP_MEMORY_SCOPE_AGENT);
        if (__all((int)(v >= tag))) break;
        if (++guard > 8192) break;  // watchdog: >>100x healthy wait, bounded worst case
        __builtin_amdgcn_s_sleep(1);
    }
}

__global__ __launch_bounds__(64, 1) void k_rnn(const int* __restrict__ x,
                                               const float* __restrict__ state,
                                               const unsigned short* __restrict__ wrt,
                                               const unsigned short* __restrict__ wzt,
                                               const unsigned short* __restrict__ wht,
                                               const float* __restrict__ W_xr, const float* __restrict__ b_r,
                                               const float* __restrict__ W_xz, const float* __restrict__ b_z,
                                               const float* __restrict__ W_xh, const float* __restrict__ b_h,
                                               const unsigned short* __restrict__ hinit, // [32][1024]
                                               unsigned short* __restrict__ hall,        // [128][32][1024]
                                               unsigned short* __restrict__ rhall,       // [128][32][1024]
                                               float* __restrict__ hstate_out,           // [32][1024]
                                               unsigned int* __restrict__ mbox) {        // [2][64][64]
    const int bid = blockIdx.x;
    const int g   = bid >> 6;
    const int jsl = bid & 63;
    const int j0  = jsl * 16;
    const int b0  = g * 16;
    const int l   = threadIdx.x;  // 0..63
    const int llo = l & 15;
    const int lhi = l >> 4;
    const int jg  = j0 + llo;

    unsigned int* gm           = mbox + g * 64 * 64;  // this group's mailbox block
    const unsigned int* myrow  = gm + jsl * 64;       // my private row (poll target)
    unsigned int* pushtgt      = gm + l * 64 + jsl;   // lane l pushes to consumer l

    __shared__ short8v wlds[3][32][64];      // 96 KB: [mat][k-subtile][lane]
    __shared__ int xs[16 * SEQ];             // 8 KB: own group's tokens
    __shared__ unsigned short pack[16 * 16]; // 512 B exchange tile

    // ---- one-time: weights -> LDS (B-frags), tokens -> LDS ----
#pragma unroll
    for (int i = 0; i < 32; i++) {
        const size_t off = (size_t)jg * HIDDEN + i * 32 + lhi * 8;
        wlds[0][i][l] = *(const short8v*)&wrt[off];
        wlds[1][i][l] = *(const short8v*)&wzt[off];
        wlds[2][i][l] = *(const short8v*)&wht[off];
    }
    for (int i = l; i < 16 * SEQ; i += 64)
        xs[i] = x[(size_t)(b0 + (i >> 7)) * SEQ + (i & 127)];

    const float brv = b_r[jg], bzv = b_z[jg], bhv = b_h[jg];
    float4v hO;
#pragma unroll
    for (int q = 0; q < 4; q++) hO[q] = state[(b0 + 4 * lhi + q) * HIDDEN + jg];
    LGKM0;  // LDS preload visible to own wave's reads

    for (int t = 0; t < SEQ; t++) {
        const unsigned short* hprev =
            t ? (hall + (size_t)(t - 1) * BATCH * HIDDEN) : hinit;
        unsigned short* rhp = rhall + (size_t)t * BATCH * HIDDEN;
        unsigned short* hp  = hall + (size_t)t * BATCH * HIDDEN;

        // embedding gathers issued BEFORE the poll (latency hides under it)
        int tok[4];
#pragma unroll
        for (int q = 0; q < 4; q++) tok[q] = xs[(4 * lhi + q) * SEQ + t];
        float xr[4], xz[4], xh[4];
#pragma unroll
        for (int q = 0; q < 4; q++) {
            xr[q] = W_xr[(size_t)tok[q] * HIDDEN + jg];
            xz[q] = W_xz[(size_t)tok[q] * HIDDEN + jg];
            xh[q] = W_xh[(size_t)tok[q] * HIDDEN + jg];
        }

        // ---- Phase A: wait h(t-1) via private row, compute r,z ----
        if (t) row_poll(myrow, 2u * (unsigned)t);

        short8v af[32];
#pragma unroll
        for (int i = 0; i < 32; i++)
            af[i] = *(const short8v*)&hprev[(b0 + llo) * HIDDEN + i * 32 + lhi * 8];

        float4v aR0 = {0.f, 0.f, 0.f, 0.f}, aR1 = {0.f, 0.f, 0.f, 0.f};
        float4v aZ0 = {0.f, 0.f, 0.f, 0.f}, aZ1 = {0.f, 0.f, 0.f, 0.f};
#pragma unroll
        for (int i = 0; i < 32; i += 2) {
            aR0 = __builtin_amdgcn_mfma_f32_16x16x32_bf16(af[i],     wlds[0][i][l],     aR0, 0, 0, 0);
            aZ0 = __builtin_amdgcn_mfma_f32_16x16x32_bf16(af[i],     wlds[1][i][l],     aZ0, 0, 0, 0);
            aR1 = __builtin_amdgcn_mfma_f32_16x16x32_bf16(af[i + 1], wlds[0][i + 1][l], aR1, 0, 0, 0);
            aZ1 = __builtin_amdgcn_mfma_f32_16x16x32_bf16(af[i + 1], wlds[1][i + 1][l], aZ1, 0, 0, 0);
        }

        float4v zv;
#pragma unroll
        for (int q = 0; q < 4; q++) {
            float sr = aR0[q] + aR1[q] + xr[q] + brv;
            float sz = aZ0[q] + aZ1[q] + xz[q] + bzv;
            float rv = 1.f / (1.f + __expf(-sr));
            zv[q]    = 1.f / (1.f + __expf(-sz));
            pack[(4 * lhi + q) * 16 + llo] = f2bf(rv * hO[q]);
        }
        LGKM0;
        __builtin_amdgcn_wave_barrier();
        {   // publish rh tile: 64x8B WT stores, drain, then push tag to all consumers
            uint2v v = *(const uint2v*)&pack[(l >> 2) * 16 + (l & 3) * 4];
            ST8_WT(&rhp[(b0 + (l >> 2)) * HIDDEN + j0 + (l & 3) * 4], v);
            WAIT_VM0;
            __hip_atomic_store(pushtgt, 2u * (unsigned)t + 1u, __ATOMIC_RELAXED,
                               __HIP_MEMORY_SCOPE_AGENT);
        }

        // ---- Phase B: wait rh via private row, compute candidate + update ----
        row_poll(myrow, 2u * (unsigned)t + 1u);

        short8v ar[32];
#pragma unroll
        for (int i = 0; i < 32; i++)
            ar[i] = *(const short8v*)&rhp[(b0 + llo) * HIDDEN + i * 32 + lhi * 8];

        float4v aC0 = {0.f, 0.f, 0.f, 0.f}, aC1 = {0.f, 0.f, 0.f, 0.f};
#pragma unroll
        for (int i = 0; i < 32; i += 2) {
            aC0 = __builtin_amdgcn_mfma_f32_16x16x32_bf16(ar[i],     wlds[2][i][l],     aC0, 0, 0, 0);
            aC1 = __builtin_amdgcn_mfma_f32_16x16x32_bf16(ar[i + 1], wlds[2][i + 1][l], aC1, 0, 0, 0);
        }
#pragma unroll
        for (int q = 0; q < 4; q++) {
            float a = aC0[q] + aC1[q] + xh[q] + bhv;
            a = fminf(15.f, fmaxf(-15.f, a));
            float e2   = __expf(2.f * a);
            float cand = (e2 - 1.f) / (e2 + 1.f);
            float hn   = zv[q] * hO[q] + (1.f - zv[q]) * cand;
            hO[q]      = hn;
            pack[(4 * lhi + q) * 16 + llo] = f2bf(hn);
        }
        LGKM0;
        __builtin_amdgcn_wave_barrier();
        {   // publish h tile into hall[t] (also the GEMM A matrix)
            uint2v v = *(const uint2v*)&pack[(l >> 2) * 16 + (l & 3) * 4];
            ST8_WT(&hp[(b0 + (l >> 2)) * HIDDEN + j0 + (l & 3) * 4], v);
            WAIT_VM0;
            __hip_atomic_store(pushtgt, 2u * (unsigned)t + 2u, __ATOMIC_RELAXED,
                               __HIP_MEMORY_SCOPE_AGENT);
        }
    }

#pragma unroll
    for (int q = 0; q < 4; q++)
        hstate_out[(b0 + 4 * lhi + q) * HIDDEN + jg] = hO[q];
}

// ---------------- output-projection GEMM ----------------
#define BM 128
#define BN 128
#define BK 64

__device__ __forceinline__ void gload_lds16(const void* g, void* l) {
    __builtin_amdgcn_global_load_lds((const __attribute__((address_space(1))) void*)g,
                                     (__attribute__((address_space(3))) void*)l, 16, 0, 0);
}

__global__ __launch_bounds__(256, 2) void k_gemm(const unsigned short* __restrict__ A,
                                                 const unsigned short* __restrict__ B,
                                                 const float* __restrict__ bo,
                                                 float* __restrict__ out) {
    __shared__ unsigned short As[BM * BK];
    __shared__ unsigned short Bs[BN * BK];
    const int wg   = blockIdx.y * 250 + blockIdx.x;
    const int swz  = (wg & 7) * 1000 + (wg >> 3);
    const int nb   = swz % 250;
    const int mb   = swz / 250;
    const int tid  = threadIdx.x;
    const int lane = tid & 63;
    const int w    = tid >> 6;
    const int wm   = w >> 1, wn = w & 1;
    const int row0 = mb * BM, col0 = nb * BN;

    float4v acc[4][4];
#pragma unroll
    for (int i = 0; i < 4; i++)
#pragma unroll
        for (int j = 0; j < 4; j++) acc[i][j] = float4v{0.f, 0.f, 0.f, 0.f};

    for (int kt = 0; kt < HIDDEN / BK; kt++) {
#pragma unroll
        for (int i = 0; i < 4; i++) {
            int s   = i * 256 + tid;
            int row = s >> 3;
            int off = (s & 7) * 8;
            gload_lds16(A + (size_t)(row0 + row) * HIDDEN + kt * BK + off, &As[s * 8]);
            gload_lds16(B + (size_t)(col0 + row) * HIDDEN + kt * BK + off, &Bs[s * 8]);
        }
        __syncthreads();
#pragma unroll
        for (int kk = 0; kk < 2; kk++) {
            short8v af[4], bf[4];
#pragma unroll
            for (int i = 0; i < 4; i++) {
                int ar = wm * 64 + i * 16 + (lane & 15);
                af[i] = *(short8v*)&As[ar * BK + kk * 32 + (lane >> 4) * 8];
                int br = wn * 64 + i * 16 + (lane & 15);
                bf[i] = *(short8v*)&Bs[br * BK + kk * 32 + (lane >> 4) * 8];
            }
#pragma unroll
            for (int i = 0; i < 4; i++)
#pragma unroll
                for (int j = 0; j < 4; j++)
                    acc[i][j] = __builtin_amdgcn_mfma_f32_16x16x32_bf16(af[i], bf[j], acc[i][j], 0, 0, 0);
        }
        __syncthreads();
    }
#pragma unroll
    for (int i = 0; i < 4; i++) {
        int grow = row0 + wm * 64 + i * 16 + (lane >> 4) * 4;
#pragma unroll
        for (int j = 0; j < 4; j++) {
            int gcol   = col0 + wn * 64 + j * 16 + (lane & 15);
            float bias = bo[gcol];
#pragma unroll
            for (int r = 0; r < 4; r++) {
                out[(size_t)(grow + r) * VOCAB + gcol] = acc[i][j][r] + bias;
            }
        }
    }
}

// ---------------- host ----------------

extern "C" void kernel_launch(void* const* d_in, const int* in_sizes, int n_in,
                              void* d_out, int out_size, void* d_ws, size_t ws_size,
                              hipStream_t stream) {
    const int*   x     = (const int*)d_in[0];
    const float* state = (const float*)d_in[1];
    const float* W_xr  = (const float*)d_in[2];
    const float* W_hr  = (const float*)d_in[3];
    const float* b_r   = (const float*)d_in[4];
    const float* W_xz  = (const float*)d_in[5];
    const float* W_hz  = (const float*)d_in[6];
    const float* b_z   = (const float*)d_in[7];
    const float* W_xh  = (const float*)d_in[8];
    const float* W_hh  = (const float*)d_in[9];
    const float* b_h   = (const float*)d_in[10];
    const float* W_ho  = (const float*)d_in[11];
    const float* b_o   = (const float*)d_in[12];

    float* out    = (float*)d_out;
    float* hstate = out + (size_t)SEQ * BATCH * VOCAB;

    // ws layout (bytes):
    //   0        : hall  bf16 [128][32][1024]   8,388,608  (= GEMM A matrix)
    //   8388608  : rhall bf16 [128][32][1024]   8,388,608
    //   16777216 : bt    bf16 [32000][1024]    65,536,000
    //   82313216 : wrt   bf16 [1024][1024]      2,097,152
    //   84410368 : wzt   bf16                   2,097,152
    //   86507520 : wht   bf16                   2,097,152
    //   88604672 : hinit bf16 [32][1024]           65,536
    //   88670208 : mbox  u32  [2][64][64]          32,768   total 88,702,976
    char* ws = (char*)d_ws;
    unsigned short* hall  = (unsigned short*)ws;
    unsigned short* rhall = (unsigned short*)(ws + 8388608);
    unsigned short* bt    = (unsigned short*)(ws + 16777216);
    unsigned short* wrt   = (unsigned short*)(ws + 82313216);
    unsigned short* wzt   = (unsigned short*)(ws + 84410368);
    unsigned short* wht   = (unsigned short*)(ws + 86507520);
    unsigned short* hinit = (unsigned short*)(ws + 88604672);
    unsigned int*   mbox  = (unsigned int*)(ws + 88670208);

    hipMemsetAsync(mbox, 0, 32768, stream);
    k_transpose_bf<<<dim3(16, 16), 256, 0, stream>>>(W_hr, wrt, HIDDEN, HIDDEN);
    k_transpose_bf<<<dim3(16, 16), 256, 0, stream>>>(W_hz, wzt, HIDDEN, HIDDEN);
    k_transpose_bf<<<dim3(16, 16), 256, 0, stream>>>(W_hh, wht, HIDDEN, HIDDEN);
    k_transpose_bf<<<dim3(500, 16), 256, 0, stream>>>(W_ho, bt, VOCAB, HIDDEN);
    k_init_hbf<<<128, 256, 0, stream>>>(state, hinit);

    k_rnn<<<128, 64, 0, stream>>>(x, state, wrt, wzt, wht, W_xr, b_r, W_xz, b_z, W_xh, b_h,
                                  hinit, hall, rhall, hstate, mbox);

    k_gemm<<<dim3(250, 32), 256, 0, stream>>>(hall, bt, b_o, out);
}